// Round 16
// baseline (62.992 us; speedup 1.0000x reference)
//
#include <hip/hip_runtime.h>

// SpinConvSq2d via MFMA (bf16). Round 16: B-amortization across pixels.
//  Invariant found across R8-R15 (all 22.8-24.8): per-CU B L1 traffic 500KB
//  (each wave reads B-frags for only 32 px) + A-LDS ~700KB vs MFMA busy
//  ~4.4us -> loop port-bound at 7.6us. This round: 64-px blocks, 4 waves =
//  {role0,role1} x {tap-half}; each wave computes BOTH y-tiles with the SAME
//  B-frags -> B L1 bytes halve. Accs double (role0 10, role1 12 f32x16 ->
//  AGPR; ~310 unified regs < 512, launch_bounds(256,2) cap 1024, no R11
//  spill). Tap-half partials merge via R12's 4-phase rowbuf epilogue +
//  R8's contiguous 32KB store. Math identical (refchecked absmax 0.0156).
// out0   = A0*(SH0*S000 + CG110*dot(s,V));  s = SH1*spin
// out1_i = A1*(s_i*S011 + SH0*T_i + CG111*cross(U,s)_i)

typedef __attribute__((ext_vector_type(8))) short short8;
typedef __attribute__((ext_vector_type(16))) float f32x16;
typedef __attribute__((ext_vector_type(4))) float float4v;

typedef __attribute__((address_space(3))) unsigned char lds_u8_t;
typedef const __attribute__((address_space(1))) unsigned char g_u8_t;

#define FEATT_BYTES (8u * 64u * 64u * 64u * 2u)   // 4 MB bf16 featT
#define BT_OFFSET   FEATT_BYTES                    // weight blob: 64000*2 B

#define MFMA32(A, B, C) __builtin_amdgcn_mfma_f32_32x32x16_bf16(A, B, C, 0, 0, 0)

template<int N> struct IC { static constexpr int value = N; };

__device__ __forceinline__ unsigned short f2bf(float f) {
    unsigned int u = __float_as_uint(f);
    return (unsigned short)((u + 0x7FFFu + ((u >> 16) & 1u)) >> 16);  // RNE
}

// ---------------- prep: featT [col][slot][y] bf16 + weight blob ----------------
__global__ __launch_bounds__(256) void prep_kernel(
    const float* __restrict__ feat,
    const float* __restrict__ W000, const float* __restrict__ W110,
    const float* __restrict__ W011, const float* __restrict__ W101,
    const float* __restrict__ W111,
    unsigned char* __restrict__ ws)
{
    int tid = threadIdx.x;
    int b = blockIdx.x;
    if (b < 512) {
        __shared__ float sf[64][68];          // 68-pad spreads banks
        size_t base = (size_t)b * 4096;       // floats (= shorts per column)
        #pragma unroll
        for (int i = 0; i < 4; ++i) {
            int e = tid + i * 256;            // float4 index 0..1023
            float4v v = *(const float4v*)(feat + base + (size_t)e * 4);
            int px = e >> 4;
            int c  = (e & 15) * 4;
            sf[px][c + 0] = v[0]; sf[px][c + 1] = v[1];
            sf[px][c + 2] = v[2]; sf[px][c + 3] = v[3];
        }
        __syncthreads();
        unsigned short* dst = (unsigned short*)ws + base;
        #pragma unroll
        for (int i = 0; i < 2; ++i) {
            int t = tid + i * 256;            // 0..511: s*64 + px
            int s = t >> 6, px = t & 63;
            short8 o;
            #pragma unroll
            for (int j = 0; j < 8; ++j) {
                int chp = s * 8 + j;
                int c = (chp < 16) ? chp : (16 + 3 * ((chp - 16) & 15) + ((chp - 16) >> 4));
                o[j] = (short)f2bf(sf[px][c]);
            }
            *(short8*)(dst + s * 512 + px * 8) = o;   // [slot][y] within column
        }
    } else {
        int t = (b - 512) * 256 + tid;        // 0..4095, need <4000
        if (t >= 4000) return;
        int a = t / 160, colv = t - a * 160;
        int arr = colv >> 5, w = colv & 31;
        const float* Wp = (arr == 0) ? W000 : (arr == 1) ? W011
                        : (arr == 2) ? W110 : (arr == 3) ? W101 : W111;
        unsigned short tmp[16];
        #pragma unroll
        for (int k = 0; k < 16; ++k) tmp[k] = f2bf(Wp[a * 512 + k * 32 + w]);
        unsigned short* d = (unsigned short*)(ws + BT_OFFSET) + (size_t)t * 16;
        *(short8*)(d)     = *(short8*)(tmp);
        *(short8*)(d + 8) = *(short8*)(tmp + 8);
    }
}

// ---------------- main MFMA kernel (64-px blocks, role x tap-half waves) ------
__global__ __launch_bounds__(256, 2) void spinconv_mfma_kernel(
    const unsigned char* __restrict__ featT8,
    const unsigned char* __restrict__ bt,
    const float* __restrict__ spin,
    float* __restrict__ out)
{
    const float SH0f   = 0.28209479177387814f;
    const float CG110f = 0.5773502691896258f;
    const float CG111f = 0.7071067811865476f;
    const float A0f    = 0.035355339059327376f;
    const float A1f    = 0.028867513459481287f;

    __shared__ __align__(16) unsigned char fl[5 * 8 * 64 * 16]; // 40KB [dx][slot][y]; reused as rowbuf
    __shared__ float s_lds[192];                                // SH1*spin (64 px)

    int tid = threadIdx.x;
    int b = blockIdx.x;
    int column = ((b & 7) << 6) + (b >> 3);   // XCD-aware remap: n*64 + x
    int x = column & 63;

    int lane = tid & 63;
    int wv = tid >> 6;             // 0..3

    // ---- async stage: 40 groups x 1KB, fully linear both sides (R7-proven) ----
    #pragma unroll
    for (int i = 0; i < 10; ++i) {
        int g = wv * 10 + i;                  // g = dx*8 + slot
        int dx = g >> 3;
        int X = (x + dx + 62) & 63;
        const unsigned char* src = featT8
            + (size_t)(column - x + X) * 8192 + (g & 7) * 1024 + lane * 16;
        __builtin_amdgcn_global_load_lds((g_u8_t*)src, (lds_u8_t*)(fl + g * 1024), 16, 0, 0);
    }
    if (tid < 192) {
        s_lds[tid] = 0.4886025119029199f * spin[(size_t)column * 192 + tid];
    }
    __syncthreads();

    int role = wv & 1;             // 0: S000,S011,V; 1: T,U
    int half = wv >> 1;            // tap-half
    int col = lane & 31;           // N-col (w) and A-row (pixel within tile)
    int khalf = lane >> 5;         // K-half select
    const unsigned char* bbase = bt + col * 32 + khalf * 16;

    f32x16 zz;
    #pragma unroll
    for (int i = 0; i < 16; ++i) zz[i] = 0.f;

    // Shared acc set (12 f32x16, union across roles; AGPR-backed):
    // role0: ac0=S000,ac1=S011,ac2=V0,ac3=V1,ac4=V2 (tile0); ac5-9 (tile1)
    // role1: ac0=T0,ac1=T1,ac2=T2,ac3=U0,ac4=U1,ac5=U2 (tile0); ac6-11 (tile1)
    f32x16 ac0 = zz, ac1 = zz, ac2 = zz, ac3 = zz, ac4 = zz, ac5 = zz;
    f32x16 ac6 = zz, ac7 = zz, ac8 = zz, ac9 = zz, ac10 = zz, ac11 = zz;

    // A-fragment loader: tile t, tap a -> ax,c0,c1,c2
    auto loadA = [&](int a, int t, short8& ax, short8& c0, short8& c1, short8& c2) {
        int ix = a / 5;
        int iy = a - ix * 5;
        int yn = ((t << 5) + col + iy + 62) & 63;
        const unsigned char* ab = fl + ix * 8192 + yn * 16;
        ax = *(const short8*)(ab + khalf * 1024);
        c0 = *(const short8*)(ab + (2 + khalf) * 1024);
        c1 = *(const short8*)(ab + (4 + khalf) * 1024);
        c2 = *(const short8*)(ab + (6 + khalf) * 1024);
    };
    auto loadAc = [&](int a, int t, short8& c0, short8& c1, short8& c2) {
        int ix = a / 5;
        int iy = a - ix * 5;
        int yn = ((t << 5) + col + iy + 62) & 63;
        const unsigned char* ab = fl + ix * 8192 + yn * 16;
        c0 = *(const short8*)(ab + (2 + khalf) * 1024);
        c1 = *(const short8*)(ab + (4 + khalf) * 1024);
        c2 = *(const short8*)(ab + (6 + khalf) * 1024);
    };

    if (role == 0) {
        auto run = [&](auto a0c, auto nc) {
            constexpr int A0T = decltype(a0c)::value;
            constexpr int END = A0T + decltype(nc)::value;
            short8 B0c, B1c, B2c, B0n, B1n, B2n;
            short8 x0c, u0c, v0c, w0c, x1c, u1c, v1c, w1c;
            short8 x0n, u0n, v0n, w0n, x1n, u1n, v1n, w1n;
            auto loadB = [&](int a, short8& b0, short8& b1, short8& b2) {
                const unsigned char* p = bbase + a * 5120;
                b0 = *(const short8*)(p);            // W000
                b1 = *(const short8*)(p + 1024);     // W011
                b2 = *(const short8*)(p + 2048);     // W110
            };
            loadB(A0T, B0c, B1c, B2c);
            loadA(A0T, 0, x0c, u0c, v0c, w0c);
            loadA(A0T, 1, x1c, u1c, v1c, w1c);
            #pragma unroll
            for (int ap = A0T; ap < END; ap += 2) {
                if (ap + 1 < END) {
                    loadB(ap + 1, B0n, B1n, B2n);
                    loadA(ap + 1, 0, x0n, u0n, v0n, w0n);
                    loadA(ap + 1, 1, x1n, u1n, v1n, w1n);
                }
                __builtin_amdgcn_s_setprio(1);
                ac0 = MFMA32(x0c, B0c, ac0);  ac1 = MFMA32(x0c, B1c, ac1);
                ac2 = MFMA32(u0c, B2c, ac2);  ac3 = MFMA32(v0c, B2c, ac3);
                ac4 = MFMA32(w0c, B2c, ac4);
                ac5 = MFMA32(x1c, B0c, ac5);  ac6 = MFMA32(x1c, B1c, ac6);
                ac7 = MFMA32(u1c, B2c, ac7);  ac8 = MFMA32(v1c, B2c, ac8);
                ac9 = MFMA32(w1c, B2c, ac9);
                __builtin_amdgcn_s_setprio(0);
                if (ap + 1 < END) {
                    if (ap + 2 < END) {
                        loadB(ap + 2, B0c, B1c, B2c);
                        loadA(ap + 2, 0, x0c, u0c, v0c, w0c);
                        loadA(ap + 2, 1, x1c, u1c, v1c, w1c);
                    }
                    __builtin_amdgcn_s_setprio(1);
                    ac0 = MFMA32(x0n, B0n, ac0);  ac1 = MFMA32(x0n, B1n, ac1);
                    ac2 = MFMA32(u0n, B2n, ac2);  ac3 = MFMA32(v0n, B2n, ac3);
                    ac4 = MFMA32(w0n, B2n, ac4);
                    ac5 = MFMA32(x1n, B0n, ac5);  ac6 = MFMA32(x1n, B1n, ac6);
                    ac7 = MFMA32(u1n, B2n, ac7);  ac8 = MFMA32(v1n, B2n, ac8);
                    ac9 = MFMA32(w1n, B2n, ac9);
                    __builtin_amdgcn_s_setprio(0);
                }
            }
        };
        if (half == 0) run(IC<0>{}, IC<13>{});
        else           run(IC<13>{}, IC<12>{});
    } else {
        auto run = [&](auto a0c, auto nc) {
            constexpr int A0T = decltype(a0c)::value;
            constexpr int END = A0T + decltype(nc)::value;
            short8 B3c, B4c, B3n, B4n;
            short8 u0c, v0c, w0c, u1c, v1c, w1c;
            short8 u0n, v0n, w0n, u1n, v1n, w1n;
            auto loadB = [&](int a, short8& b3, short8& b4) {
                const unsigned char* p = bbase + a * 5120;
                b3 = *(const short8*)(p + 3072);     // W101
                b4 = *(const short8*)(p + 4096);     // W111
            };
            loadB(A0T, B3c, B4c);
            loadAc(A0T, 0, u0c, v0c, w0c);
            loadAc(A0T, 1, u1c, v1c, w1c);
            #pragma unroll
            for (int ap = A0T; ap < END; ap += 2) {
                if (ap + 1 < END) {
                    loadB(ap + 1, B3n, B4n);
                    loadAc(ap + 1, 0, u0n, v0n, w0n);
                    loadAc(ap + 1, 1, u1n, v1n, w1n);
                }
                __builtin_amdgcn_s_setprio(1);
                ac0 = MFMA32(u0c, B3c, ac0);  ac3 = MFMA32(u0c, B4c, ac3);
                ac1 = MFMA32(v0c, B3c, ac1);  ac4 = MFMA32(v0c, B4c, ac4);
                ac2 = MFMA32(w0c, B3c, ac2);  ac5 = MFMA32(w0c, B4c, ac5);
                ac6 = MFMA32(u1c, B3c, ac6);  ac9 = MFMA32(u1c, B4c, ac9);
                ac7 = MFMA32(v1c, B3c, ac7);  ac10 = MFMA32(v1c, B4c, ac10);
                ac8 = MFMA32(w1c, B3c, ac8);  ac11 = MFMA32(w1c, B4c, ac11);
                __builtin_amdgcn_s_setprio(0);
                if (ap + 1 < END) {
                    if (ap + 2 < END) {
                        loadB(ap + 2, B3c, B4c);
                        loadAc(ap + 2, 0, u0c, v0c, w0c);
                        loadAc(ap + 2, 1, u1c, v1c, w1c);
                    }
                    __builtin_amdgcn_s_setprio(1);
                    ac0 = MFMA32(u0n, B3n, ac0);  ac3 = MFMA32(u0n, B4n, ac3);
                    ac1 = MFMA32(v0n, B3n, ac1);  ac4 = MFMA32(v0n, B4n, ac4);
                    ac2 = MFMA32(w0n, B3n, ac2);  ac5 = MFMA32(w0n, B4n, ac5);
                    ac6 = MFMA32(u1n, B3n, ac6);  ac9 = MFMA32(u1n, B4n, ac9);
                    ac7 = MFMA32(v1n, B3n, ac7);  ac10 = MFMA32(v1n, B4n, ac10);
                    ac8 = MFMA32(w1n, B3n, ac8);  ac11 = MFMA32(w1n, B4n, ac11);
                    __builtin_amdgcn_s_setprio(0);
                }
            }
        };
        if (half == 0) run(IC<0>{}, IC<12>{});
        else           run(IC<12>{}, IC<13>{});
    }

    __syncthreads();   // tap loops done: fl dead -> reuse as rowbuf [64][128]
    float* rowbuf = (float*)fl;

    // ---- 4-phase partial deposits (order: wv0 init, wv2 +=, wv1 +=, wv3 +=) ----
    // C/D row = (r&3)+8*(r>>2)+4*khalf; pxin = t*32 + row.
    if (wv == 0) {     // role0 half0: init
        #pragma unroll
        for (int r = 0; r < 16; ++r) {
            int row = (r & 3) + ((r >> 2) << 3) + (khalf << 2);
            #pragma unroll
            for (int t = 0; t < 2; ++t) {
                int y = (t << 5) + row;
                float s0 = s_lds[y * 3 + 0], s1 = s_lds[y * 3 + 1], s2 = s_lds[y * 3 + 2];
                float S000 = t ? ac5[r] : ac0[r];
                float S011 = t ? ac6[r] : ac1[r];
                float V0 = t ? ac7[r] : ac2[r];
                float V1 = t ? ac8[r] : ac3[r];
                float V2 = t ? ac9[r] : ac4[r];
                float* rb = rowbuf + y * 128;
                float* rp = rb + 32 + 3 * col;
                rb[col] = A0f * (SH0f * S000 + CG110f * (s0 * V0 + s1 * V1 + s2 * V2));
                rp[0] = A1f * s0 * S011;
                rp[1] = A1f * s1 * S011;
                rp[2] = A1f * s2 * S011;
            }
        }
    }
    __syncthreads();
    if (wv == 2) {     // role0 half1: accumulate
        #pragma unroll
        for (int r = 0; r < 16; ++r) {
            int row = (r & 3) + ((r >> 2) << 3) + (khalf << 2);
            #pragma unroll
            for (int t = 0; t < 2; ++t) {
                int y = (t << 5) + row;
                float s0 = s_lds[y * 3 + 0], s1 = s_lds[y * 3 + 1], s2 = s_lds[y * 3 + 2];
                float S000 = t ? ac5[r] : ac0[r];
                float S011 = t ? ac6[r] : ac1[r];
                float V0 = t ? ac7[r] : ac2[r];
                float V1 = t ? ac8[r] : ac3[r];
                float V2 = t ? ac9[r] : ac4[r];
                float* rb = rowbuf + y * 128;
                float* rp = rb + 32 + 3 * col;
                rb[col] += A0f * (SH0f * S000 + CG110f * (s0 * V0 + s1 * V1 + s2 * V2));
                rp[0] += A1f * s0 * S011;
                rp[1] += A1f * s1 * S011;
                rp[2] += A1f * s2 * S011;
            }
        }
    }
    __syncthreads();
    if (wv == 1) {     // role1 half0: accumulate T,U terms
        #pragma unroll
        for (int r = 0; r < 16; ++r) {
            int row = (r & 3) + ((r >> 2) << 3) + (khalf << 2);
            #pragma unroll
            for (int t = 0; t < 2; ++t) {
                int y = (t << 5) + row;
                float s0 = s_lds[y * 3 + 0], s1 = s_lds[y * 3 + 1], s2 = s_lds[y * 3 + 2];
                float T0 = t ? ac6[r] : ac0[r];
                float T1 = t ? ac7[r] : ac1[r];
                float T2 = t ? ac8[r] : ac2[r];
                float U0 = t ? ac9[r] : ac3[r];
                float U1 = t ? ac10[r] : ac4[r];
                float U2 = t ? ac11[r] : ac5[r];
                float* rp = rowbuf + y * 128 + 32 + 3 * col;
                rp[0] += A1f * (SH0f * T0 + CG111f * (U1 * s2 - U2 * s1));
                rp[1] += A1f * (SH0f * T1 + CG111f * (U2 * s0 - U0 * s2));
                rp[2] += A1f * (SH0f * T2 + CG111f * (U0 * s1 - U1 * s0));
            }
        }
    }
    __syncthreads();
    if (wv == 3) {     // role1 half1: accumulate T,U terms
        #pragma unroll
        for (int r = 0; r < 16; ++r) {
            int row = (r & 3) + ((r >> 2) << 3) + (khalf << 2);
            #pragma unroll
            for (int t = 0; t < 2; ++t) {
                int y = (t << 5) + row;
                float s0 = s_lds[y * 3 + 0], s1 = s_lds[y * 3 + 1], s2 = s_lds[y * 3 + 2];
                float T0 = t ? ac6[r] : ac0[r];
                float T1 = t ? ac7[r] : ac1[r];
                float T2 = t ? ac8[r] : ac2[r];
                float U0 = t ? ac9[r] : ac3[r];
                float U1 = t ? ac10[r] : ac4[r];
                float U2 = t ? ac11[r] : ac5[r];
                float* rp = rowbuf + y * 128 + 32 + 3 * col;
                rp[0] += A1f * (SH0f * T0 + CG111f * (U1 * s2 - U2 * s1));
                rp[1] += A1f * (SH0f * T1 + CG111f * (U2 * s0 - U0 * s2));
                rp[2] += A1f * (SH0f * T2 + CG111f * (U0 * s1 - U1 * s0));
            }
        }
    }
    __syncthreads();

    // ---- cooperative contiguous store: 64 rows x 512B = 32KB ----
    float* ob = out + (size_t)column * 64 * 128;
    #pragma unroll
    for (int i = 0; i < 8; ++i) {
        int e = (tid + (i << 8)) << 2;        // float offset, 16B-aligned
        *(float4v*)(ob + e) = *(const float4v*)(rowbuf + e);
    }
}

extern "C" void kernel_launch(void* const* d_in, const int* in_sizes, int n_in,
                              void* d_out, int out_size, void* d_ws, size_t ws_size,
                              hipStream_t stream) {
    const float* feat = (const float*)d_in[0];
    const float* spin = (const float*)d_in[1];
    const float* W000 = (const float*)d_in[2];
    const float* W110 = (const float*)d_in[3];
    const float* W011 = (const float*)d_in[4];
    const float* W101 = (const float*)d_in[5];
    const float* W111 = (const float*)d_in[6];
    float* out = (float*)d_out;
    unsigned char* ws = (unsigned char*)d_ws;

    hipLaunchKernelGGL(prep_kernel, dim3(528), dim3(256), 0, stream,
                       feat, W000, W110, W011, W101, W111, ws);
    hipLaunchKernelGGL(spinconv_mfma_kernel, dim3(512), dim3(256), 0, stream,
                       ws, ws + BT_OFFSET, spin, out);
}